// Round 3
// baseline (120.279 us; speedup 1.0000x reference)
//
#include <hip/hip_runtime.h>
#include <math.h>

#define NB 7
#define EPS_ 0.02f
#define ITERS1_ 120   // mantissa/exponent phase (replaces log-domain phase)
#define ITERS2_ 80    // multiplicative phase; total 200 == reference count.
// R12/R14 calibration: reference@200 is NOT converged; trajectory matching at
// exactly 200 iterations is mandatory; truncation and early exit are dead.
// THIS-SESSION R1: switch@96 FAILED (absmax 1.6e-2): rescue events still fire
// in iters (96,120]. Switch point stays at 120.
// THIS-SESSION R3: phase 1 rewritten from log-domain (exp2/log2, rescue
// branches) to (f32 mantissa, i32 exponent) multiplicative form. Same math
// (always-max-recentered LSE, like jax logsumexp), unbounded dynamic range,
// zero transcendentals except rcp. Rounding trajectory differs from the R8
// log-domain path — validated by this round's absmax.
#define TINY_ 1e-40f
#define LOG2E_ 1.4426950408889634f
#define LN2_   0.6931471805599453f

// Bare hardware transcendentals (base-2 domain).
__device__ __forceinline__ float exp2_hw(float x) {
#if __has_builtin(__builtin_amdgcn_exp2f)
    return __builtin_amdgcn_exp2f(x);
#else
    return __expf(x * LN2_);
#endif
}
__device__ __forceinline__ float log2_hw(float x) {
#if __has_builtin(__builtin_amdgcn_logf)
    return __builtin_amdgcn_logf(x);
#else
    return __logf(x) * LOG2E_;
#endif
}
__device__ __forceinline__ float rcp_hw(float x) {
#if __has_builtin(__builtin_amdgcn_rcpf)
    return __builtin_amdgcn_rcpf(x);
#else
    return 1.0f / x;
#endif
}
// Full-rate (non-transcendental) scale/normalize ops.
__device__ __forceinline__ float ldexp_hw(float x, int e) {
#if __has_builtin(__builtin_amdgcn_ldexpf)
    return __builtin_amdgcn_ldexpf(x, e);
#else
    float r; asm("v_ldexp_f32 %0, %1, %2" : "=v"(r) : "v"(x), "v"(e)); return r;
#endif
}
__device__ __forceinline__ float frexp_mant_hw(float x) {
#if __has_builtin(__builtin_amdgcn_frexp_mantf)
    return __builtin_amdgcn_frexp_mantf(x);
#else
    float r; asm("v_frexp_mant_f32 %0, %1" : "=v"(r) : "v"(x)); return r;
#endif
}
__device__ __forceinline__ int frexp_exp_hw(float x) {
#if __has_builtin(__builtin_amdgcn_frexp_expf)
    return __builtin_amdgcn_frexp_expf(x);
#else
    int r; asm("v_frexp_exp_i32_f32 %0, %1" : "=v"(r) : "v"(x)); return r;
#endif
}

// ---- DPP helpers ----
template <int CTRL>
__device__ __forceinline__ float dpp_ident(float identity, float x) {
    return __int_as_float(__builtin_amdgcn_update_dpp(
        __float_as_int(identity), __float_as_int(x), CTRL, 0xF, 0xF, false));
}
__device__ __forceinline__ float readlane63(float x) {
    return __int_as_float(__builtin_amdgcn_readlane(__float_as_int(x), 63));
}
__device__ __forceinline__ float wave_sum_bcast(float s) {
    s += dpp_ident<0x111>(0.f, s);
    s += dpp_ident<0x112>(0.f, s);
    s += dpp_ident<0x114>(0.f, s);
    s += dpp_ident<0x118>(0.f, s);
    s += dpp_ident<0x142>(0.f, s);
    s += dpp_ident<0x143>(0.f, s);
    return readlane63(s);
}

// 7-column interleaved 64-lane INT-MAX reduce (keep-old DPP semantics for the
// partial-row_mask bcast stages). Source-preserving first stage (no movs).
// Inputs v0..v6: int VGPRs; outputs m0..m6: wave-uniform SGPR ints.
#define WAVE_MAXI7(v0,v1,v2,v3,v4,v5,v6, m0,m1,m2,m3,m4,m5,m6)               \
  {                                                                           \
    int r0,r1,r2,r3,r4,r5,r6;                                                 \
    asm("v_max_i32_dpp %0, %14, %14 row_shr:1 row_mask:0xf bank_mask:0xf\n\t" \
        "v_max_i32_dpp %1, %15, %15 row_shr:1 row_mask:0xf bank_mask:0xf\n\t" \
        "v_max_i32_dpp %2, %16, %16 row_shr:1 row_mask:0xf bank_mask:0xf\n\t" \
        "v_max_i32_dpp %3, %17, %17 row_shr:1 row_mask:0xf bank_mask:0xf\n\t" \
        "v_max_i32_dpp %4, %18, %18 row_shr:1 row_mask:0xf bank_mask:0xf\n\t" \
        "v_max_i32_dpp %5, %19, %19 row_shr:1 row_mask:0xf bank_mask:0xf\n\t" \
        "v_max_i32_dpp %6, %20, %20 row_shr:1 row_mask:0xf bank_mask:0xf\n\t" \
        "v_max_i32_dpp %0, %0, %0 row_shr:2 row_mask:0xf bank_mask:0xf\n\t"   \
        "v_max_i32_dpp %1, %1, %1 row_shr:2 row_mask:0xf bank_mask:0xf\n\t"   \
        "v_max_i32_dpp %2, %2, %2 row_shr:2 row_mask:0xf bank_mask:0xf\n\t"   \
        "v_max_i32_dpp %3, %3, %3 row_shr:2 row_mask:0xf bank_mask:0xf\n\t"   \
        "v_max_i32_dpp %4, %4, %4 row_shr:2 row_mask:0xf bank_mask:0xf\n\t"   \
        "v_max_i32_dpp %5, %5, %5 row_shr:2 row_mask:0xf bank_mask:0xf\n\t"   \
        "v_max_i32_dpp %6, %6, %6 row_shr:2 row_mask:0xf bank_mask:0xf\n\t"   \
        "v_max_i32_dpp %0, %0, %0 row_shr:4 row_mask:0xf bank_mask:0xf\n\t"   \
        "v_max_i32_dpp %1, %1, %1 row_shr:4 row_mask:0xf bank_mask:0xf\n\t"   \
        "v_max_i32_dpp %2, %2, %2 row_shr:4 row_mask:0xf bank_mask:0xf\n\t"   \
        "v_max_i32_dpp %3, %3, %3 row_shr:4 row_mask:0xf bank_mask:0xf\n\t"   \
        "v_max_i32_dpp %4, %4, %4 row_shr:4 row_mask:0xf bank_mask:0xf\n\t"   \
        "v_max_i32_dpp %5, %5, %5 row_shr:4 row_mask:0xf bank_mask:0xf\n\t"   \
        "v_max_i32_dpp %6, %6, %6 row_shr:4 row_mask:0xf bank_mask:0xf\n\t"   \
        "v_max_i32_dpp %0, %0, %0 row_shr:8 row_mask:0xf bank_mask:0xf\n\t"   \
        "v_max_i32_dpp %1, %1, %1 row_shr:8 row_mask:0xf bank_mask:0xf\n\t"   \
        "v_max_i32_dpp %2, %2, %2 row_shr:8 row_mask:0xf bank_mask:0xf\n\t"   \
        "v_max_i32_dpp %3, %3, %3 row_shr:8 row_mask:0xf bank_mask:0xf\n\t"   \
        "v_max_i32_dpp %4, %4, %4 row_shr:8 row_mask:0xf bank_mask:0xf\n\t"   \
        "v_max_i32_dpp %5, %5, %5 row_shr:8 row_mask:0xf bank_mask:0xf\n\t"   \
        "v_max_i32_dpp %6, %6, %6 row_shr:8 row_mask:0xf bank_mask:0xf\n\t"   \
        "v_max_i32_dpp %0, %0, %0 row_bcast:15 row_mask:0xa bank_mask:0xf\n\t"\
        "v_max_i32_dpp %1, %1, %1 row_bcast:15 row_mask:0xa bank_mask:0xf\n\t"\
        "v_max_i32_dpp %2, %2, %2 row_bcast:15 row_mask:0xa bank_mask:0xf\n\t"\
        "v_max_i32_dpp %3, %3, %3 row_bcast:15 row_mask:0xa bank_mask:0xf\n\t"\
        "v_max_i32_dpp %4, %4, %4 row_bcast:15 row_mask:0xa bank_mask:0xf\n\t"\
        "v_max_i32_dpp %5, %5, %5 row_bcast:15 row_mask:0xa bank_mask:0xf\n\t"\
        "v_max_i32_dpp %6, %6, %6 row_bcast:15 row_mask:0xa bank_mask:0xf\n\t"\
        "v_max_i32_dpp %0, %0, %0 row_bcast:31 row_mask:0xc bank_mask:0xf\n\t"\
        "v_max_i32_dpp %1, %1, %1 row_bcast:31 row_mask:0xc bank_mask:0xf\n\t"\
        "v_max_i32_dpp %2, %2, %2 row_bcast:31 row_mask:0xc bank_mask:0xf\n\t"\
        "v_max_i32_dpp %3, %3, %3 row_bcast:31 row_mask:0xc bank_mask:0xf\n\t"\
        "v_max_i32_dpp %4, %4, %4 row_bcast:31 row_mask:0xc bank_mask:0xf\n\t"\
        "v_max_i32_dpp %5, %5, %5 row_bcast:31 row_mask:0xc bank_mask:0xf\n\t"\
        "v_max_i32_dpp %6, %6, %6 row_bcast:31 row_mask:0xc bank_mask:0xf\n\t"\
        "v_readlane_b32 %7, %0, 63\n\t"                                       \
        "v_readlane_b32 %8, %1, 63\n\t"                                       \
        "v_readlane_b32 %9, %2, 63\n\t"                                       \
        "v_readlane_b32 %10, %3, 63\n\t"                                      \
        "v_readlane_b32 %11, %4, 63\n\t"                                      \
        "v_readlane_b32 %12, %5, 63\n\t"                                      \
        "v_readlane_b32 %13, %6, 63\n\t"                                      \
        "s_nop 1"                                                             \
        : "=&v"(r0), "=&v"(r1), "=&v"(r2), "=&v"(r3),                         \
          "=&v"(r4), "=&v"(r5), "=&v"(r6),                                    \
          "=s"(m0), "=s"(m1), "=s"(m2), "=s"(m3),                             \
          "=s"(m4), "=s"(m5), "=s"(m6)                                        \
        : "v"(v0), "v"(v1), "v"(v2), "v"(v3), "v"(v4), "v"(v5), "v"(v6));     \
  }

// 7-column interleaved 64-lane SUM reduce; e0..e6 clobbered; sums -> SGPRs.
#define WAVE_SUM7(e0,e1,e2,e3,e4,e5,e6, s0_,s1_,s2_,s3_,s4_,s5_,s6_)          \
    asm("s_nop 1\n\t"                                                         \
        "v_add_f32_dpp %0, %0, %0 row_shr:1 row_mask:0xf bank_mask:0xf\n\t"   \
        "v_add_f32_dpp %1, %1, %1 row_shr:1 row_mask:0xf bank_mask:0xf\n\t"   \
        "v_add_f32_dpp %2, %2, %2 row_shr:1 row_mask:0xf bank_mask:0xf\n\t"   \
        "v_add_f32_dpp %3, %3, %3 row_shr:1 row_mask:0xf bank_mask:0xf\n\t"   \
        "v_add_f32_dpp %4, %4, %4 row_shr:1 row_mask:0xf bank_mask:0xf\n\t"   \
        "v_add_f32_dpp %5, %5, %5 row_shr:1 row_mask:0xf bank_mask:0xf\n\t"   \
        "v_add_f32_dpp %6, %6, %6 row_shr:1 row_mask:0xf bank_mask:0xf\n\t"   \
        "v_add_f32_dpp %0, %0, %0 row_shr:2 row_mask:0xf bank_mask:0xf\n\t"   \
        "v_add_f32_dpp %1, %1, %1 row_shr:2 row_mask:0xf bank_mask:0xf\n\t"   \
        "v_add_f32_dpp %2, %2, %2 row_shr:2 row_mask:0xf bank_mask:0xf\n\t"   \
        "v_add_f32_dpp %3, %3, %3 row_shr:2 row_mask:0xf bank_mask:0xf\n\t"   \
        "v_add_f32_dpp %4, %4, %4 row_shr:2 row_mask:0xf bank_mask:0xf\n\t"   \
        "v_add_f32_dpp %5, %5, %5 row_shr:2 row_mask:0xf bank_mask:0xf\n\t"   \
        "v_add_f32_dpp %6, %6, %6 row_shr:2 row_mask:0xf bank_mask:0xf\n\t"   \
        "v_add_f32_dpp %0, %0, %0 row_shr:4 row_mask:0xf bank_mask:0xf\n\t"   \
        "v_add_f32_dpp %1, %1, %1 row_shr:4 row_mask:0xf bank_mask:0xf\n\t"   \
        "v_add_f32_dpp %2, %2, %2 row_shr:4 row_mask:0xf bank_mask:0xf\n\t"   \
        "v_add_f32_dpp %3, %3, %3 row_shr:4 row_mask:0xf bank_mask:0xf\n\t"   \
        "v_add_f32_dpp %4, %4, %4 row_shr:4 row_mask:0xf bank_mask:0xf\n\t"   \
        "v_add_f32_dpp %5, %5, %5 row_shr:4 row_mask:0xf bank_mask:0xf\n\t"   \
        "v_add_f32_dpp %6, %6, %6 row_shr:4 row_mask:0xf bank_mask:0xf\n\t"   \
        "v_add_f32_dpp %0, %0, %0 row_shr:8 row_mask:0xf bank_mask:0xf\n\t"   \
        "v_add_f32_dpp %1, %1, %1 row_shr:8 row_mask:0xf bank_mask:0xf\n\t"   \
        "v_add_f32_dpp %2, %2, %2 row_shr:8 row_mask:0xf bank_mask:0xf\n\t"   \
        "v_add_f32_dpp %3, %3, %3 row_shr:8 row_mask:0xf bank_mask:0xf\n\t"   \
        "v_add_f32_dpp %4, %4, %4 row_shr:8 row_mask:0xf bank_mask:0xf\n\t"   \
        "v_add_f32_dpp %5, %5, %5 row_shr:8 row_mask:0xf bank_mask:0xf\n\t"   \
        "v_add_f32_dpp %6, %6, %6 row_shr:8 row_mask:0xf bank_mask:0xf\n\t"   \
        "v_add_f32_dpp %0, %0, %0 row_bcast:15 row_mask:0xa bank_mask:0xf\n\t"\
        "v_add_f32_dpp %1, %1, %1 row_bcast:15 row_mask:0xa bank_mask:0xf\n\t"\
        "v_add_f32_dpp %2, %2, %2 row_bcast:15 row_mask:0xa bank_mask:0xf\n\t"\
        "v_add_f32_dpp %3, %3, %3 row_bcast:15 row_mask:0xa bank_mask:0xf\n\t"\
        "v_add_f32_dpp %4, %4, %4 row_bcast:15 row_mask:0xa bank_mask:0xf\n\t"\
        "v_add_f32_dpp %5, %5, %5 row_bcast:15 row_mask:0xa bank_mask:0xf\n\t"\
        "v_add_f32_dpp %6, %6, %6 row_bcast:15 row_mask:0xa bank_mask:0xf\n\t"\
        "v_add_f32_dpp %0, %0, %0 row_bcast:31 row_mask:0xc bank_mask:0xf\n\t"\
        "v_add_f32_dpp %1, %1, %1 row_bcast:31 row_mask:0xc bank_mask:0xf\n\t"\
        "v_add_f32_dpp %2, %2, %2 row_bcast:31 row_mask:0xc bank_mask:0xf\n\t"\
        "v_add_f32_dpp %3, %3, %3 row_bcast:31 row_mask:0xc bank_mask:0xf\n\t"\
        "v_add_f32_dpp %4, %4, %4 row_bcast:31 row_mask:0xc bank_mask:0xf\n\t"\
        "v_add_f32_dpp %5, %5, %5 row_bcast:31 row_mask:0xc bank_mask:0xf\n\t"\
        "v_add_f32_dpp %6, %6, %6 row_bcast:31 row_mask:0xc bank_mask:0xf\n\t"\
        "v_readlane_b32 %7, %0, 63\n\t"                                       \
        "v_readlane_b32 %8, %1, 63\n\t"                                       \
        "v_readlane_b32 %9, %2, 63\n\t"                                       \
        "v_readlane_b32 %10, %3, 63\n\t"                                      \
        "v_readlane_b32 %11, %4, 63\n\t"                                      \
        "v_readlane_b32 %12, %5, 63\n\t"                                      \
        "v_readlane_b32 %13, %6, 63\n\t"                                      \
        "s_nop 1"                                                             \
        : "+v"(e0), "+v"(e1), "+v"(e2), "+v"(e3),                             \
          "+v"(e4), "+v"(e5), "+v"(e6),                                       \
          "=s"(s0_), "=s"(s1_), "=s"(s2_), "=s"(s3_),                         \
          "=s"(s4_), "=s"(s5_), "=s"(s6_))

// Same reduce but SOURCE-PRESERVING (first stage reads sources into fresh
// scratch). Bit-identical arithmetic; saves 7 v_mov per call.
#define WAVE_SUM7_SRC(w0,w1,w2,w3,w4,w5,w6, s0_,s1_,s2_,s3_,s4_,s5_,s6_)     \
  {                                                                           \
    float r0,r1,r2,r3,r4,r5,r6;                                               \
    asm("s_nop 1\n\t"                                                         \
        "v_add_f32_dpp %0, %14, %14 row_shr:1 row_mask:0xf bank_mask:0xf\n\t" \
        "v_add_f32_dpp %1, %15, %15 row_shr:1 row_mask:0xf bank_mask:0xf\n\t" \
        "v_add_f32_dpp %2, %16, %16 row_shr:1 row_mask:0xf bank_mask:0xf\n\t" \
        "v_add_f32_dpp %3, %17, %17 row_shr:1 row_mask:0xf bank_mask:0xf\n\t" \
        "v_add_f32_dpp %4, %18, %18 row_shr:1 row_mask:0xf bank_mask:0xf\n\t" \
        "v_add_f32_dpp %5, %19, %19 row_shr:1 row_mask:0xf bank_mask:0xf\n\t" \
        "v_add_f32_dpp %6, %20, %20 row_shr:1 row_mask:0xf bank_mask:0xf\n\t" \
        "v_add_f32_dpp %0, %0, %0 row_shr:2 row_mask:0xf bank_mask:0xf\n\t"   \
        "v_add_f32_dpp %1, %1, %1 row_shr:2 row_mask:0xf bank_mask:0xf\n\t"   \
        "v_add_f32_dpp %2, %2, %2 row_shr:2 row_mask:0xf bank_mask:0xf\n\t"   \
        "v_add_f32_dpp %3, %3, %3 row_shr:2 row_mask:0xf bank_mask:0xf\n\t"   \
        "v_add_f32_dpp %4, %4, %4 row_shr:2 row_mask:0xf bank_mask:0xf\n\t"   \
        "v_add_f32_dpp %5, %5, %5 row_shr:2 row_mask:0xf bank_mask:0xf\n\t"   \
        "v_add_f32_dpp %6, %6, %6 row_shr:2 row_mask:0xf bank_mask:0xf\n\t"   \
        "v_add_f32_dpp %0, %0, %0 row_shr:4 row_mask:0xf bank_mask:0xf\n\t"   \
        "v_add_f32_dpp %1, %1, %1 row_shr:4 row_mask:0xf bank_mask:0xf\n\t"   \
        "v_add_f32_dpp %2, %2, %2 row_shr:4 row_mask:0xf bank_mask:0xf\n\t"   \
        "v_add_f32_dpp %3, %3, %3 row_shr:4 row_mask:0xf bank_mask:0xf\n\t"   \
        "v_add_f32_dpp %4, %4, %4 row_shr:4 row_mask:0xf bank_mask:0xf\n\t"   \
        "v_add_f32_dpp %5, %5, %5 row_shr:4 row_mask:0xf bank_mask:0xf\n\t"   \
        "v_add_f32_dpp %6, %6, %6 row_shr:4 row_mask:0xf bank_mask:0xf\n\t"   \
        "v_add_f32_dpp %0, %0, %0 row_shr:8 row_mask:0xf bank_mask:0xf\n\t"   \
        "v_add_f32_dpp %1, %1, %1 row_shr:8 row_mask:0xf bank_mask:0xf\n\t"   \
        "v_add_f32_dpp %2, %2, %2 row_shr:8 row_mask:0xf bank_mask:0xf\n\t"   \
        "v_add_f32_dpp %3, %3, %3 row_shr:8 row_mask:0xf bank_mask:0xf\n\t"   \
        "v_add_f32_dpp %4, %4, %4 row_shr:8 row_mask:0xf bank_mask:0xf\n\t"   \
        "v_add_f32_dpp %5, %5, %5 row_shr:8 row_mask:0xf bank_mask:0xf\n\t"   \
        "v_add_f32_dpp %6, %6, %6 row_shr:8 row_mask:0xf bank_mask:0xf\n\t"   \
        "v_add_f32_dpp %0, %0, %0 row_bcast:15 row_mask:0xa bank_mask:0xf\n\t"\
        "v_add_f32_dpp %1, %1, %1 row_bcast:15 row_mask:0xa bank_mask:0xf\n\t"\
        "v_add_f32_dpp %2, %2, %2 row_bcast:15 row_mask:0xa bank_mask:0xf\n\t"\
        "v_add_f32_dpp %3, %3, %3 row_bcast:15 row_mask:0xa bank_mask:0xf\n\t"\
        "v_add_f32_dpp %4, %4, %4 row_bcast:15 row_mask:0xa bank_mask:0xf\n\t"\
        "v_add_f32_dpp %5, %5, %5 row_bcast:15 row_mask:0xa bank_mask:0xf\n\t"\
        "v_add_f32_dpp %6, %6, %6 row_bcast:15 row_mask:0xa bank_mask:0xf\n\t"\
        "v_add_f32_dpp %0, %0, %0 row_bcast:31 row_mask:0xc bank_mask:0xf\n\t"\
        "v_add_f32_dpp %1, %1, %1 row_bcast:31 row_mask:0xc bank_mask:0xf\n\t"\
        "v_add_f32_dpp %2, %2, %2 row_bcast:31 row_mask:0xc bank_mask:0xf\n\t"\
        "v_add_f32_dpp %3, %3, %3 row_bcast:31 row_mask:0xc bank_mask:0xf\n\t"\
        "v_add_f32_dpp %4, %4, %4 row_bcast:31 row_mask:0xc bank_mask:0xf\n\t"\
        "v_add_f32_dpp %5, %5, %5 row_bcast:31 row_mask:0xc bank_mask:0xf\n\t"\
        "v_add_f32_dpp %6, %6, %6 row_bcast:31 row_mask:0xc bank_mask:0xf\n\t"\
        "v_readlane_b32 %7, %0, 63\n\t"                                       \
        "v_readlane_b32 %8, %1, 63\n\t"                                       \
        "v_readlane_b32 %9, %2, 63\n\t"                                       \
        "v_readlane_b32 %10, %3, 63\n\t"                                      \
        "v_readlane_b32 %11, %4, 63\n\t"                                      \
        "v_readlane_b32 %12, %5, 63\n\t"                                      \
        "v_readlane_b32 %13, %6, 63\n\t"                                      \
        "s_nop 1"                                                             \
        : "=&v"(r0), "=&v"(r1), "=&v"(r2), "=&v"(r3),                         \
          "=&v"(r4), "=&v"(r5), "=&v"(r6),                                    \
          "=s"(s0_), "=s"(s1_), "=s"(s2_), "=s"(s3_),                         \
          "=s"(s4_), "=s"(s5_), "=s"(s6_)                                     \
        : "v"(w0), "v"(w1), "v"(w2), "v"(w3), "v"(w4), "v"(w5), "v"(w6));     \
  }

__global__ __launch_bounds__(64) void sinkhorn_kernel(
    const float* __restrict__ theta,  // [64,7]
    const float* __restrict__ phi,    // [7]
    const float* __restrict__ n,      // [64]
    const float* __restrict__ sens,   // [64]
    const float* __restrict__ err,    // [7]
    float* __restrict__ out)          // [64,7]
{
    const int lane = threadIdx.x;     // one wave: lane == row

    const float ni = n[lane];
    const float si = sens[lane];

    // Base-2 domain. K2 = (theta - C)*log2e/EPS.
    const float kscale = LOG2E_ / EPS_;
    float K2[NB];
    #pragma unroll
    for (int j = 0; j < NB; ++j)
        K2[j] = (theta[lane * NB + j] - ni * si * err[j]) * kscale;

    const float nsum   = wave_sum_bcast(ni);
    const float aT     = ni / nsum + TINY_;
    const float log_a2 = log2_hw(aT);

    // log_b2 = log2(softmax(phi) + TINY)  (uniform; per lane)
    float t2v[NB];
    #pragma unroll
    for (int j = 0; j < NB; ++j) t2v[j] = phi[j] * LOG2E_;
    float pmax = t2v[0];
    #pragma unroll
    for (int j = 1; j < NB; ++j) pmax = fmaxf(pmax, t2v[j]);
    float psum = 0.f;
    #pragma unroll
    for (int j = 0; j < NB; ++j) psum += exp2_hw(t2v[j] - pmax);
    const float lps = log2_hw(psum);
    float bT[NB], cb[NB];
    #pragma unroll
    for (int j = 0; j < NB; ++j) {
        bT[j]     = exp2_hw(t2v[j] - pmax - lps) + TINY_;
        const float log_b2 = log2_hw(bT[j]);
        cb[j]     = log_b2 - log_a2;
    }
    // Multiplicative constants: b2 = 2^cb, ib = 2^-cb.
    float b2c[NB], ibc[NB];
    #pragma unroll
    for (int j = 0; j < NB; ++j) {
        b2c[j] = exp2_hw(cb[j]);
        ibc[j] = exp2_hw(-cb[j]);
    }

    // ---- Phase 1: mantissa/exponent Sinkhorn, 120 iterations.
    // State: E_j = M_j * 2^{iE_j}  (== 2^{t_j + cb_j} of the log-domain form).
    // Row:   s_true = s * 2^X, X = max_j iE (per lane). s in [1,14) always.
    // e_j   = E_j * ib_j / s_true = g_j * 2^{xe_j},  g = M*ib*rcp(s).
    // Col:   Xc_j = cross-lane max of xe_j; h = ldexp(g, xe-Xc); ss = colsum h.
    // E'_j  = e_j * b2_j / ss_true = (g*rcp(ss)*b2) * 2^{xe-Xc} -> frexp-renorm.
    // All mantissa-path quantities provably in normal f32 range: no rescues,
    // no branches, no transcendentals except rcp.
    float Mm[NB]; int iE[NB];
    #pragma unroll
    for (int j = 0; j < NB; ++j) {
        const float y  = K2[j] - log_a2;      // t0 + cb
        const float yi = rintf(y);
        iE[j] = (int)yi;
        Mm[j] = exp2_hw(y - yi);              // in [2^-0.5, 2^0.5]
    }

    for (int it = 0; it < ITERS1_; ++it) {
        // per-lane (row) max exponent
        const int X = max(max(max(iE[0], iE[1]), max(iE[2], iE[3])),
                          max(max(iE[4], iE[5]), iE[6]));
        const int xe0 = iE[0]-X, xe1 = iE[1]-X, xe2 = iE[2]-X, xe3 = iE[3]-X,
                  xe4 = iE[4]-X, xe5 = iE[5]-X, xe6 = iE[6]-X;
        const float f0 = ldexp_hw(Mm[0], xe0), f1 = ldexp_hw(Mm[1], xe1),
                    f2 = ldexp_hw(Mm[2], xe2), f3 = ldexp_hw(Mm[3], xe3),
                    f4 = ldexp_hw(Mm[4], xe4), f5 = ldexp_hw(Mm[5], xe5),
                    f6 = ldexp_hw(Mm[6], xe6);
        const float s  = ((f0 + f1) + (f2 + f3)) + ((f4 + f5) + f6); // [1,14)
        const float rs = rcp_hw(s);

        // cross-lane (column) max of exponents -> SGPR; issued here so the
        // 49-op DPP block covers the rcp latency.
        int C0, C1, C2, C3, C4, C5, C6;
        WAVE_MAXI7(xe0, xe1, xe2, xe3, xe4, xe5, xe6,
                   C0, C1, C2, C3, C4, C5, C6);

        const float g0 = (Mm[0]*ibc[0])*rs, g1 = (Mm[1]*ibc[1])*rs,
                    g2 = (Mm[2]*ibc[2])*rs, g3 = (Mm[3]*ibc[3])*rs,
                    g4 = (Mm[4]*ibc[4])*rs, g5 = (Mm[5]*ibc[5])*rs,
                    g6 = (Mm[6]*ibc[6])*rs;
        const int d0 = xe0-C0, d1 = xe1-C1, d2 = xe2-C2, d3 = xe3-C3,
                  d4 = xe4-C4, d5 = xe5-C5, d6 = xe6-C6;
        float h0 = ldexp_hw(g0, d0), h1 = ldexp_hw(g1, d1),
              h2 = ldexp_hw(g2, d2), h3 = ldexp_hw(g3, d3),
              h4 = ldexp_hw(g4, d4), h5 = ldexp_hw(g5, d5),
              h6 = ldexp_hw(g6, d6);

        float ss0, ss1, ss2, ss3, ss4, ss5, ss6;
        WAVE_SUM7(h0, h1, h2, h3, h4, h5, h6,
                  ss0, ss1, ss2, ss3, ss4, ss5, ss6);

        const float r0 = rcp_hw(ss0), r1 = rcp_hw(ss1), r2 = rcp_hw(ss2),
                    r3 = rcp_hw(ss3), r4 = rcp_hw(ss4), r5 = rcp_hw(ss5),
                    r6 = rcp_hw(ss6);
        const float w0 = (g0*r0)*b2c[0], w1 = (g1*r1)*b2c[1],
                    w2 = (g2*r2)*b2c[2], w3 = (g3*r3)*b2c[3],
                    w4 = (g4*r4)*b2c[4], w5 = (g5*r5)*b2c[5],
                    w6 = (g6*r6)*b2c[6];
        Mm[0] = frexp_mant_hw(w0); iE[0] = frexp_exp_hw(w0) + d0;
        Mm[1] = frexp_mant_hw(w1); iE[1] = frexp_exp_hw(w1) + d1;
        Mm[2] = frexp_mant_hw(w2); iE[2] = frexp_exp_hw(w2) + d2;
        Mm[3] = frexp_mant_hw(w3); iE[3] = frexp_exp_hw(w3) + d3;
        Mm[4] = frexp_mant_hw(w4); iE[4] = frexp_exp_hw(w4) + d4;
        Mm[5] = frexp_mant_hw(w5); iE[5] = frexp_exp_hw(w5) + d5;
        Mm[6] = frexp_mant_hw(w6); iE[6] = frexp_exp_hw(w6) + d6;
    }

    // ---- Switch: U = 2^t = E * 2^-cb = ldexp(M*ib, iE); underflow -> 0,
    // same semantics as exp2(t). ----
    float U[NB], B[NB];
    #pragma unroll
    for (int j = 0; j < NB; ++j) {
        U[j] = ldexp_hw(Mm[j] * ibc[j], iE[j]);
        B[j] = b2c[j];
    }

    // ---- Phase 2: multiplicative, 80 iterations (unchanged body). ----
    for (int it = 0; it < ITERS2_; ++it) {
        float p0 = U[0] * B[0], p1 = U[1] * B[1], p2 = U[2] * B[2],
              p3 = U[3] * B[3], p4 = U[4] * B[4], p5 = U[5] * B[5],
              p6 = U[6] * B[6];
        const float s = ((p0 + p1) + (p2 + p3)) + ((p4 + p5) + p6);
        const float rs = rcp_hw(s);
        float w0 = U[0] * rs, w1 = U[1] * rs, w2 = U[2] * rs,
              w3 = U[3] * rs, w4 = U[4] * rs, w5 = U[5] * rs,
              w6 = U[6] * rs;

        float ss0, ss1, ss2, ss3, ss4, ss5, ss6;
        WAVE_SUM7_SRC(w0, w1, w2, w3, w4, w5, w6,
                      ss0, ss1, ss2, ss3, ss4, ss5, ss6);

        const float r0 = rcp_hw(ss0);
        const float r1 = rcp_hw(ss1);
        const float r2 = rcp_hw(ss2);
        const float r3 = rcp_hw(ss3);
        const float r4 = rcp_hw(ss4);
        const float r5 = rcp_hw(ss5);
        const float r6 = rcp_hw(ss6);
        U[0] = w0 * r0; U[1] = w1 * r1; U[2] = w2 * r2; U[3] = w3 * r3;
        U[4] = w4 * r4; U[5] = w5 * r5; U[6] = w6 * r6;
    }

    // ---- Epilogue: P = U * bT; normalize by total (+TINY) ----
    float pr[NB];
    float rowsum = 0.f;
    #pragma unroll
    for (int j = 0; j < NB; ++j) {
        pr[j] = U[j] * bT[j];
        rowsum += pr[j];
    }
    const float total = wave_sum_bcast(rowsum);   // ~1 at convergence
    const float inv = 1.0f / (total + TINY_);
    #pragma unroll
    for (int j = 0; j < NB; ++j)
        out[lane * NB + j] = pr[j] * inv;
}

extern "C" void kernel_launch(void* const* d_in, const int* in_sizes, int n_in,
                              void* d_out, int out_size, void* d_ws, size_t ws_size,
                              hipStream_t stream) {
    const float* theta = (const float*)d_in[0];
    const float* phi   = (const float*)d_in[1];
    const float* n     = (const float*)d_in[2];
    const float* sens  = (const float*)d_in[3];
    const float* err   = (const float*)d_in[4];
    float* out = (float*)d_out;

    sinkhorn_kernel<<<1, 64, 0, stream>>>(theta, phi, n, sens, err, out);
}

// Round 4
// 113.846 us; speedup vs baseline: 1.0565x; 1.0565x over previous
//
#include <hip/hip_runtime.h>
#include <math.h>

#define NB 7
#define EPS_ 0.02f
#define ITERS1_ 120   // mantissa/exponent phase
#define ITERS2_ 80    // multiplicative phase; total 200 == reference count.
// R12/R14 calibration: reference@200 is NOT converged; trajectory matching at
// exactly 200 iterations is mandatory; truncation and early exit are dead.
// THIS-SESSION R1: switch@96 FAILED (absmax 1.6e-2). Switch point stays at 120.
// THIS-SESSION R3: phase 1 = (f32 mantissa, i32 exponent) multiplicative form,
// PASSED (absmax 1.525879e-05) but 63.1us: two 49-op DPP blocks/iter.
// THIS-SESSION R4: stale column scale XcS (SGPR) + SALU window check on ss
// bit patterns; WAVE_MAXI7 only on rescue. State update proven bit-invariant
// to Xc within +-80 of true max (ldexp exact, sum scale-invariant, rcp
// exact-scaling, frexp_exp+d cancels offset) => trajectory bit-identical to
// R3. Expected absmax: exactly 1.525879e-05.
#define TINY_ 1e-40f
#define LOG2E_ 1.4426950408889634f
#define LN2_   0.6931471805599453f

// Bare hardware transcendentals (base-2 domain).
__device__ __forceinline__ float exp2_hw(float x) {
#if __has_builtin(__builtin_amdgcn_exp2f)
    return __builtin_amdgcn_exp2f(x);
#else
    return __expf(x * LN2_);
#endif
}
__device__ __forceinline__ float log2_hw(float x) {
#if __has_builtin(__builtin_amdgcn_logf)
    return __builtin_amdgcn_logf(x);
#else
    return __logf(x) * LOG2E_;
#endif
}
__device__ __forceinline__ float rcp_hw(float x) {
#if __has_builtin(__builtin_amdgcn_rcpf)
    return __builtin_amdgcn_rcpf(x);
#else
    return 1.0f / x;
#endif
}
// Full-rate (non-transcendental) scale/normalize ops.
__device__ __forceinline__ float ldexp_hw(float x, int e) {
#if __has_builtin(__builtin_amdgcn_ldexpf)
    return __builtin_amdgcn_ldexpf(x, e);
#else
    float r; asm("v_ldexp_f32 %0, %1, %2" : "=v"(r) : "v"(x), "v"(e)); return r;
#endif
}
__device__ __forceinline__ float frexp_mant_hw(float x) {
#if __has_builtin(__builtin_amdgcn_frexp_mantf)
    return __builtin_amdgcn_frexp_mantf(x);
#else
    float r; asm("v_frexp_mant_f32 %0, %1" : "=v"(r) : "v"(x)); return r;
#endif
}
__device__ __forceinline__ int frexp_exp_hw(float x) {
#if __has_builtin(__builtin_amdgcn_frexp_expf)
    return __builtin_amdgcn_frexp_expf(x);
#else
    int r; asm("v_frexp_exp_i32_f32 %0, %1" : "=v"(r) : "v"(x)); return r;
#endif
}

// ---- DPP helpers ----
template <int CTRL>
__device__ __forceinline__ float dpp_ident(float identity, float x) {
    return __int_as_float(__builtin_amdgcn_update_dpp(
        __float_as_int(identity), __float_as_int(x), CTRL, 0xF, 0xF, false));
}
__device__ __forceinline__ float readlane63(float x) {
    return __int_as_float(__builtin_amdgcn_readlane(__float_as_int(x), 63));
}
__device__ __forceinline__ float wave_sum_bcast(float s) {
    s += dpp_ident<0x111>(0.f, s);
    s += dpp_ident<0x112>(0.f, s);
    s += dpp_ident<0x114>(0.f, s);
    s += dpp_ident<0x118>(0.f, s);
    s += dpp_ident<0x142>(0.f, s);
    s += dpp_ident<0x143>(0.f, s);
    return readlane63(s);
}

// 7-column interleaved 64-lane INT-MAX reduce; results -> wave-uniform SGPRs.
// Source-preserving first stage. Rescue-path only.
#define WAVE_MAXI7(v0,v1,v2,v3,v4,v5,v6, m0,m1,m2,m3,m4,m5,m6)               \
  {                                                                           \
    int r0,r1,r2,r3,r4,r5,r6;                                                 \
    asm("v_max_i32_dpp %0, %14, %14 row_shr:1 row_mask:0xf bank_mask:0xf\n\t" \
        "v_max_i32_dpp %1, %15, %15 row_shr:1 row_mask:0xf bank_mask:0xf\n\t" \
        "v_max_i32_dpp %2, %16, %16 row_shr:1 row_mask:0xf bank_mask:0xf\n\t" \
        "v_max_i32_dpp %3, %17, %17 row_shr:1 row_mask:0xf bank_mask:0xf\n\t" \
        "v_max_i32_dpp %4, %18, %18 row_shr:1 row_mask:0xf bank_mask:0xf\n\t" \
        "v_max_i32_dpp %5, %19, %19 row_shr:1 row_mask:0xf bank_mask:0xf\n\t" \
        "v_max_i32_dpp %6, %20, %20 row_shr:1 row_mask:0xf bank_mask:0xf\n\t" \
        "v_max_i32_dpp %0, %0, %0 row_shr:2 row_mask:0xf bank_mask:0xf\n\t"   \
        "v_max_i32_dpp %1, %1, %1 row_shr:2 row_mask:0xf bank_mask:0xf\n\t"   \
        "v_max_i32_dpp %2, %2, %2 row_shr:2 row_mask:0xf bank_mask:0xf\n\t"   \
        "v_max_i32_dpp %3, %3, %3 row_shr:2 row_mask:0xf bank_mask:0xf\n\t"   \
        "v_max_i32_dpp %4, %4, %4 row_shr:2 row_mask:0xf bank_mask:0xf\n\t"   \
        "v_max_i32_dpp %5, %5, %5 row_shr:2 row_mask:0xf bank_mask:0xf\n\t"   \
        "v_max_i32_dpp %6, %6, %6 row_shr:2 row_mask:0xf bank_mask:0xf\n\t"   \
        "v_max_i32_dpp %0, %0, %0 row_shr:4 row_mask:0xf bank_mask:0xf\n\t"   \
        "v_max_i32_dpp %1, %1, %1 row_shr:4 row_mask:0xf bank_mask:0xf\n\t"   \
        "v_max_i32_dpp %2, %2, %2 row_shr:4 row_mask:0xf bank_mask:0xf\n\t"   \
        "v_max_i32_dpp %3, %3, %3 row_shr:4 row_mask:0xf bank_mask:0xf\n\t"   \
        "v_max_i32_dpp %4, %4, %4 row_shr:4 row_mask:0xf bank_mask:0xf\n\t"   \
        "v_max_i32_dpp %5, %5, %5 row_shr:4 row_mask:0xf bank_mask:0xf\n\t"   \
        "v_max_i32_dpp %6, %6, %6 row_shr:4 row_mask:0xf bank_mask:0xf\n\t"   \
        "v_max_i32_dpp %0, %0, %0 row_shr:8 row_mask:0xf bank_mask:0xf\n\t"   \
        "v_max_i32_dpp %1, %1, %1 row_shr:8 row_mask:0xf bank_mask:0xf\n\t"   \
        "v_max_i32_dpp %2, %2, %2 row_shr:8 row_mask:0xf bank_mask:0xf\n\t"   \
        "v_max_i32_dpp %3, %3, %3 row_shr:8 row_mask:0xf bank_mask:0xf\n\t"   \
        "v_max_i32_dpp %4, %4, %4 row_shr:8 row_mask:0xf bank_mask:0xf\n\t"   \
        "v_max_i32_dpp %5, %5, %5 row_shr:8 row_mask:0xf bank_mask:0xf\n\t"   \
        "v_max_i32_dpp %6, %6, %6 row_shr:8 row_mask:0xf bank_mask:0xf\n\t"   \
        "v_max_i32_dpp %0, %0, %0 row_bcast:15 row_mask:0xa bank_mask:0xf\n\t"\
        "v_max_i32_dpp %1, %1, %1 row_bcast:15 row_mask:0xa bank_mask:0xf\n\t"\
        "v_max_i32_dpp %2, %2, %2 row_bcast:15 row_mask:0xa bank_mask:0xf\n\t"\
        "v_max_i32_dpp %3, %3, %3 row_bcast:15 row_mask:0xa bank_mask:0xf\n\t"\
        "v_max_i32_dpp %4, %4, %4 row_bcast:15 row_mask:0xa bank_mask:0xf\n\t"\
        "v_max_i32_dpp %5, %5, %5 row_bcast:15 row_mask:0xa bank_mask:0xf\n\t"\
        "v_max_i32_dpp %6, %6, %6 row_bcast:15 row_mask:0xa bank_mask:0xf\n\t"\
        "v_max_i32_dpp %0, %0, %0 row_bcast:31 row_mask:0xc bank_mask:0xf\n\t"\
        "v_max_i32_dpp %1, %1, %1 row_bcast:31 row_mask:0xc bank_mask:0xf\n\t"\
        "v_max_i32_dpp %2, %2, %2 row_bcast:31 row_mask:0xc bank_mask:0xf\n\t"\
        "v_max_i32_dpp %3, %3, %3 row_bcast:31 row_mask:0xc bank_mask:0xf\n\t"\
        "v_max_i32_dpp %4, %4, %4 row_bcast:31 row_mask:0xc bank_mask:0xf\n\t"\
        "v_max_i32_dpp %5, %5, %5 row_bcast:31 row_mask:0xc bank_mask:0xf\n\t"\
        "v_max_i32_dpp %6, %6, %6 row_bcast:31 row_mask:0xc bank_mask:0xf\n\t"\
        "v_readlane_b32 %7, %0, 63\n\t"                                       \
        "v_readlane_b32 %8, %1, 63\n\t"                                       \
        "v_readlane_b32 %9, %2, 63\n\t"                                       \
        "v_readlane_b32 %10, %3, 63\n\t"                                      \
        "v_readlane_b32 %11, %4, 63\n\t"                                      \
        "v_readlane_b32 %12, %5, 63\n\t"                                      \
        "v_readlane_b32 %13, %6, 63\n\t"                                      \
        "s_nop 1"                                                             \
        : "=&v"(r0), "=&v"(r1), "=&v"(r2), "=&v"(r3),                         \
          "=&v"(r4), "=&v"(r5), "=&v"(r6),                                    \
          "=s"(m0), "=s"(m1), "=s"(m2), "=s"(m3),                             \
          "=s"(m4), "=s"(m5), "=s"(m6)                                        \
        : "v"(v0), "v"(v1), "v"(v2), "v"(v3), "v"(v4), "v"(v5), "v"(v6));     \
  }

// 7-column interleaved 64-lane SUM reduce; e0..e6 clobbered; sums -> SGPRs.
#define WAVE_SUM7(e0,e1,e2,e3,e4,e5,e6, s0_,s1_,s2_,s3_,s4_,s5_,s6_)          \
    asm("s_nop 1\n\t"                                                         \
        "v_add_f32_dpp %0, %0, %0 row_shr:1 row_mask:0xf bank_mask:0xf\n\t"   \
        "v_add_f32_dpp %1, %1, %1 row_shr:1 row_mask:0xf bank_mask:0xf\n\t"   \
        "v_add_f32_dpp %2, %2, %2 row_shr:1 row_mask:0xf bank_mask:0xf\n\t"   \
        "v_add_f32_dpp %3, %3, %3 row_shr:1 row_mask:0xf bank_mask:0xf\n\t"   \
        "v_add_f32_dpp %4, %4, %4 row_shr:1 row_mask:0xf bank_mask:0xf\n\t"   \
        "v_add_f32_dpp %5, %5, %5 row_shr:1 row_mask:0xf bank_mask:0xf\n\t"   \
        "v_add_f32_dpp %6, %6, %6 row_shr:1 row_mask:0xf bank_mask:0xf\n\t"   \
        "v_add_f32_dpp %0, %0, %0 row_shr:2 row_mask:0xf bank_mask:0xf\n\t"   \
        "v_add_f32_dpp %1, %1, %1 row_shr:2 row_mask:0xf bank_mask:0xf\n\t"   \
        "v_add_f32_dpp %2, %2, %2 row_shr:2 row_mask:0xf bank_mask:0xf\n\t"   \
        "v_add_f32_dpp %3, %3, %3 row_shr:2 row_mask:0xf bank_mask:0xf\n\t"   \
        "v_add_f32_dpp %4, %4, %4 row_shr:2 row_mask:0xf bank_mask:0xf\n\t"   \
        "v_add_f32_dpp %5, %5, %5 row_shr:2 row_mask:0xf bank_mask:0xf\n\t"   \
        "v_add_f32_dpp %6, %6, %6 row_shr:2 row_mask:0xf bank_mask:0xf\n\t"   \
        "v_add_f32_dpp %0, %0, %0 row_shr:4 row_mask:0xf bank_mask:0xf\n\t"   \
        "v_add_f32_dpp %1, %1, %1 row_shr:4 row_mask:0xf bank_mask:0xf\n\t"   \
        "v_add_f32_dpp %2, %2, %2 row_shr:4 row_mask:0xf bank_mask:0xf\n\t"   \
        "v_add_f32_dpp %3, %3, %3 row_shr:4 row_mask:0xf bank_mask:0xf\n\t"   \
        "v_add_f32_dpp %4, %4, %4 row_shr:4 row_mask:0xf bank_mask:0xf\n\t"   \
        "v_add_f32_dpp %5, %5, %5 row_shr:4 row_mask:0xf bank_mask:0xf\n\t"   \
        "v_add_f32_dpp %6, %6, %6 row_shr:4 row_mask:0xf bank_mask:0xf\n\t"   \
        "v_add_f32_dpp %0, %0, %0 row_shr:8 row_mask:0xf bank_mask:0xf\n\t"   \
        "v_add_f32_dpp %1, %1, %1 row_shr:8 row_mask:0xf bank_mask:0xf\n\t"   \
        "v_add_f32_dpp %2, %2, %2 row_shr:8 row_mask:0xf bank_mask:0xf\n\t"   \
        "v_add_f32_dpp %3, %3, %3 row_shr:8 row_mask:0xf bank_mask:0xf\n\t"   \
        "v_add_f32_dpp %4, %4, %4 row_shr:8 row_mask:0xf bank_mask:0xf\n\t"   \
        "v_add_f32_dpp %5, %5, %5 row_shr:8 row_mask:0xf bank_mask:0xf\n\t"   \
        "v_add_f32_dpp %6, %6, %6 row_shr:8 row_mask:0xf bank_mask:0xf\n\t"   \
        "v_add_f32_dpp %0, %0, %0 row_bcast:15 row_mask:0xa bank_mask:0xf\n\t"\
        "v_add_f32_dpp %1, %1, %1 row_bcast:15 row_mask:0xa bank_mask:0xf\n\t"\
        "v_add_f32_dpp %2, %2, %2 row_bcast:15 row_mask:0xa bank_mask:0xf\n\t"\
        "v_add_f32_dpp %3, %3, %3 row_bcast:15 row_mask:0xa bank_mask:0xf\n\t"\
        "v_add_f32_dpp %4, %4, %4 row_bcast:15 row_mask:0xa bank_mask:0xf\n\t"\
        "v_add_f32_dpp %5, %5, %5 row_bcast:15 row_mask:0xa bank_mask:0xf\n\t"\
        "v_add_f32_dpp %6, %6, %6 row_bcast:15 row_mask:0xa bank_mask:0xf\n\t"\
        "v_add_f32_dpp %0, %0, %0 row_bcast:31 row_mask:0xc bank_mask:0xf\n\t"\
        "v_add_f32_dpp %1, %1, %1 row_bcast:31 row_mask:0xc bank_mask:0xf\n\t"\
        "v_add_f32_dpp %2, %2, %2 row_bcast:31 row_mask:0xc bank_mask:0xf\n\t"\
        "v_add_f32_dpp %3, %3, %3 row_bcast:31 row_mask:0xc bank_mask:0xf\n\t"\
        "v_add_f32_dpp %4, %4, %4 row_bcast:31 row_mask:0xc bank_mask:0xf\n\t"\
        "v_add_f32_dpp %5, %5, %5 row_bcast:31 row_mask:0xc bank_mask:0xf\n\t"\
        "v_add_f32_dpp %6, %6, %6 row_bcast:31 row_mask:0xc bank_mask:0xf\n\t"\
        "v_readlane_b32 %7, %0, 63\n\t"                                       \
        "v_readlane_b32 %8, %1, 63\n\t"                                       \
        "v_readlane_b32 %9, %2, 63\n\t"                                       \
        "v_readlane_b32 %10, %3, 63\n\t"                                      \
        "v_readlane_b32 %11, %4, 63\n\t"                                      \
        "v_readlane_b32 %12, %5, 63\n\t"                                      \
        "v_readlane_b32 %13, %6, 63\n\t"                                      \
        "s_nop 1"                                                             \
        : "+v"(e0), "+v"(e1), "+v"(e2), "+v"(e3),                             \
          "+v"(e4), "+v"(e5), "+v"(e6),                                       \
          "=s"(s0_), "=s"(s1_), "=s"(s2_), "=s"(s3_),                         \
          "=s"(s4_), "=s"(s5_), "=s"(s6_))

// Same reduce but SOURCE-PRESERVING (first stage reads sources into fresh
// scratch). Bit-identical arithmetic; saves 7 v_mov per call.
#define WAVE_SUM7_SRC(w0,w1,w2,w3,w4,w5,w6, s0_,s1_,s2_,s3_,s4_,s5_,s6_)     \
  {                                                                           \
    float r0,r1,r2,r3,r4,r5,r6;                                               \
    asm("s_nop 1\n\t"                                                         \
        "v_add_f32_dpp %0, %14, %14 row_shr:1 row_mask:0xf bank_mask:0xf\n\t" \
        "v_add_f32_dpp %1, %15, %15 row_shr:1 row_mask:0xf bank_mask:0xf\n\t" \
        "v_add_f32_dpp %2, %16, %16 row_shr:1 row_mask:0xf bank_mask:0xf\n\t" \
        "v_add_f32_dpp %3, %17, %17 row_shr:1 row_mask:0xf bank_mask:0xf\n\t" \
        "v_add_f32_dpp %4, %18, %18 row_shr:1 row_mask:0xf bank_mask:0xf\n\t" \
        "v_add_f32_dpp %5, %19, %19 row_shr:1 row_mask:0xf bank_mask:0xf\n\t" \
        "v_add_f32_dpp %6, %20, %20 row_shr:1 row_mask:0xf bank_mask:0xf\n\t" \
        "v_add_f32_dpp %0, %0, %0 row_shr:2 row_mask:0xf bank_mask:0xf\n\t"   \
        "v_add_f32_dpp %1, %1, %1 row_shr:2 row_mask:0xf bank_mask:0xf\n\t"   \
        "v_add_f32_dpp %2, %2, %2 row_shr:2 row_mask:0xf bank_mask:0xf\n\t"   \
        "v_add_f32_dpp %3, %3, %3 row_shr:2 row_mask:0xf bank_mask:0xf\n\t"   \
        "v_add_f32_dpp %4, %4, %4 row_shr:2 row_mask:0xf bank_mask:0xf\n\t"   \
        "v_add_f32_dpp %5, %5, %5 row_shr:2 row_mask:0xf bank_mask:0xf\n\t"   \
        "v_add_f32_dpp %6, %6, %6 row_shr:2 row_mask:0xf bank_mask:0xf\n\t"   \
        "v_add_f32_dpp %0, %0, %0 row_shr:4 row_mask:0xf bank_mask:0xf\n\t"   \
        "v_add_f32_dpp %1, %1, %1 row_shr:4 row_mask:0xf bank_mask:0xf\n\t"   \
        "v_add_f32_dpp %2, %2, %2 row_shr:4 row_mask:0xf bank_mask:0xf\n\t"   \
        "v_add_f32_dpp %3, %3, %3 row_shr:4 row_mask:0xf bank_mask:0xf\n\t"   \
        "v_add_f32_dpp %4, %4, %4 row_shr:4 row_mask:0xf bank_mask:0xf\n\t"   \
        "v_add_f32_dpp %5, %5, %5 row_shr:4 row_mask:0xf bank_mask:0xf\n\t"   \
        "v_add_f32_dpp %6, %6, %6 row_shr:4 row_mask:0xf bank_mask:0xf\n\t"   \
        "v_add_f32_dpp %0, %0, %0 row_shr:8 row_mask:0xf bank_mask:0xf\n\t"   \
        "v_add_f32_dpp %1, %1, %1 row_shr:8 row_mask:0xf bank_mask:0xf\n\t"   \
        "v_add_f32_dpp %2, %2, %2 row_shr:8 row_mask:0xf bank_mask:0xf\n\t"   \
        "v_add_f32_dpp %3, %3, %3 row_shr:8 row_mask:0xf bank_mask:0xf\n\t"   \
        "v_add_f32_dpp %4, %4, %4 row_shr:8 row_mask:0xf bank_mask:0xf\n\t"   \
        "v_add_f32_dpp %5, %5, %5 row_shr:8 row_mask:0xf bank_mask:0xf\n\t"   \
        "v_add_f32_dpp %6, %6, %6 row_shr:8 row_mask:0xf bank_mask:0xf\n\t"   \
        "v_add_f32_dpp %0, %0, %0 row_bcast:15 row_mask:0xa bank_mask:0xf\n\t"\
        "v_add_f32_dpp %1, %1, %1 row_bcast:15 row_mask:0xa bank_mask:0xf\n\t"\
        "v_add_f32_dpp %2, %2, %2 row_bcast:15 row_mask:0xa bank_mask:0xf\n\t"\
        "v_add_f32_dpp %3, %3, %3 row_bcast:15 row_mask:0xa bank_mask:0xf\n\t"\
        "v_add_f32_dpp %4, %4, %4 row_bcast:15 row_mask:0xa bank_mask:0xf\n\t"\
        "v_add_f32_dpp %5, %5, %5 row_bcast:15 row_mask:0xa bank_mask:0xf\n\t"\
        "v_add_f32_dpp %6, %6, %6 row_bcast:15 row_mask:0xa bank_mask:0xf\n\t"\
        "v_add_f32_dpp %0, %0, %0 row_bcast:31 row_mask:0xc bank_mask:0xf\n\t"\
        "v_add_f32_dpp %1, %1, %1 row_bcast:31 row_mask:0xc bank_mask:0xf\n\t"\
        "v_add_f32_dpp %2, %2, %2 row_bcast:31 row_mask:0xc bank_mask:0xf\n\t"\
        "v_add_f32_dpp %3, %3, %3 row_bcast:31 row_mask:0xc bank_mask:0xf\n\t"\
        "v_add_f32_dpp %4, %4, %4 row_bcast:31 row_mask:0xc bank_mask:0xf\n\t"\
        "v_add_f32_dpp %5, %5, %5 row_bcast:31 row_mask:0xc bank_mask:0xf\n\t"\
        "v_add_f32_dpp %6, %6, %6 row_bcast:31 row_mask:0xc bank_mask:0xf\n\t"\
        "v_readlane_b32 %7, %0, 63\n\t"                                       \
        "v_readlane_b32 %8, %1, 63\n\t"                                       \
        "v_readlane_b32 %9, %2, 63\n\t"                                       \
        "v_readlane_b32 %10, %3, 63\n\t"                                      \
        "v_readlane_b32 %11, %4, 63\n\t"                                      \
        "v_readlane_b32 %12, %5, 63\n\t"                                      \
        "v_readlane_b32 %13, %6, 63\n\t"                                      \
        "s_nop 1"                                                             \
        : "=&v"(r0), "=&v"(r1), "=&v"(r2), "=&v"(r3),                         \
          "=&v"(r4), "=&v"(r5), "=&v"(r6),                                    \
          "=s"(s0_), "=s"(s1_), "=s"(s2_), "=s"(s3_),                         \
          "=s"(s4_), "=s"(s5_), "=s"(s6_)                                     \
        : "v"(w0), "v"(w1), "v"(w2), "v"(w3), "v"(w4), "v"(w5), "v"(w6));     \
  }

__global__ __launch_bounds__(64) void sinkhorn_kernel(
    const float* __restrict__ theta,  // [64,7]
    const float* __restrict__ phi,    // [7]
    const float* __restrict__ n,      // [64]
    const float* __restrict__ sens,   // [64]
    const float* __restrict__ err,    // [7]
    float* __restrict__ out)          // [64,7]
{
    const int lane = threadIdx.x;     // one wave: lane == row

    const float ni = n[lane];
    const float si = sens[lane];

    // Base-2 domain. K2 = (theta - C)*log2e/EPS.
    const float kscale = LOG2E_ / EPS_;
    float K2[NB];
    #pragma unroll
    for (int j = 0; j < NB; ++j)
        K2[j] = (theta[lane * NB + j] - ni * si * err[j]) * kscale;

    const float nsum   = wave_sum_bcast(ni);
    const float aT     = ni / nsum + TINY_;
    const float log_a2 = log2_hw(aT);

    // log_b2 = log2(softmax(phi) + TINY)  (uniform; per lane)
    float t2v[NB];
    #pragma unroll
    for (int j = 0; j < NB; ++j) t2v[j] = phi[j] * LOG2E_;
    float pmax = t2v[0];
    #pragma unroll
    for (int j = 1; j < NB; ++j) pmax = fmaxf(pmax, t2v[j]);
    float psum = 0.f;
    #pragma unroll
    for (int j = 0; j < NB; ++j) psum += exp2_hw(t2v[j] - pmax);
    const float lps = log2_hw(psum);
    float bT[NB], cb[NB];
    #pragma unroll
    for (int j = 0; j < NB; ++j) {
        bT[j]     = exp2_hw(t2v[j] - pmax - lps) + TINY_;
        const float log_b2 = log2_hw(bT[j]);
        cb[j]     = log_b2 - log_a2;
    }
    // Multiplicative constants: b2 = 2^cb, ib = 2^-cb.
    float b2c[NB], ibc[NB];
    #pragma unroll
    for (int j = 0; j < NB; ++j) {
        b2c[j] = exp2_hw(cb[j]);
        ibc[j] = exp2_hw(-cb[j]);
    }

    // ---- Phase 1: mantissa/exponent Sinkhorn, 120 iterations.
    // State: E_j = M_j * 2^{iE_j}. Row scaling by per-lane max exponent
    // (cheap). Column scaling by STALE per-column SGPR scale XcS; the ss
    // window check [2^-80, 2^80] on SGPR bit patterns guarantees the update
    // is bit-identical to the exact-max version (ldexp exact, f32 sum
    // scale-invariant, rcp exact-scaling, frexp_exp + d cancels the offset).
    // Out-of-window -> rescue: exact WAVE_MAXI7 + redo sum, refresh XcS.
    float Mm[NB]; int iE[NB];
    #pragma unroll
    for (int j = 0; j < NB; ++j) {
        const float y  = K2[j] - log_a2;      // t0 + cb
        const float yi = rintf(y);
        iE[j] = (int)yi;
        Mm[j] = exp2_hw(y - yi);              // in [2^-0.5, 2^0.5]
    }

    int XcS0 = 0, XcS1 = 0, XcS2 = 0, XcS3 = 0, XcS4 = 0, XcS5 = 0, XcS6 = 0;
    const unsigned SLO = 0x17800000u, SHI = 0x67800000u;  // [2^-80, 2^80]

    for (int it = 0; it < ITERS1_; ++it) {
        // per-lane (row) max exponent + row-normalized sum
        const int X = max(max(max(iE[0], iE[1]), max(iE[2], iE[3])),
                          max(max(iE[4], iE[5]), iE[6]));
        const int xe0 = iE[0]-X, xe1 = iE[1]-X, xe2 = iE[2]-X, xe3 = iE[3]-X,
                  xe4 = iE[4]-X, xe5 = iE[5]-X, xe6 = iE[6]-X;
        const float f0 = ldexp_hw(Mm[0], xe0), f1 = ldexp_hw(Mm[1], xe1),
                    f2 = ldexp_hw(Mm[2], xe2), f3 = ldexp_hw(Mm[3], xe3),
                    f4 = ldexp_hw(Mm[4], xe4), f5 = ldexp_hw(Mm[5], xe5),
                    f6 = ldexp_hw(Mm[6], xe6);
        const float s  = ((f0 + f1) + (f2 + f3)) + ((f4 + f5) + f6); // [1,14)
        const float rs = rcp_hw(s);

        const float g0 = (Mm[0]*ibc[0])*rs, g1 = (Mm[1]*ibc[1])*rs,
                    g2 = (Mm[2]*ibc[2])*rs, g3 = (Mm[3]*ibc[3])*rs,
                    g4 = (Mm[4]*ibc[4])*rs, g5 = (Mm[5]*ibc[5])*rs,
                    g6 = (Mm[6]*ibc[6])*rs;

        // Fast path: align with the STALE column scale.
        int d0 = xe0-XcS0, d1 = xe1-XcS1, d2 = xe2-XcS2, d3 = xe3-XcS3,
            d4 = xe4-XcS4, d5 = xe5-XcS5, d6 = xe6-XcS6;
        float h0 = ldexp_hw(g0, d0), h1 = ldexp_hw(g1, d1),
              h2 = ldexp_hw(g2, d2), h3 = ldexp_hw(g3, d3),
              h4 = ldexp_hw(g4, d4), h5 = ldexp_hw(g5, d5),
              h6 = ldexp_hw(g6, d6);

        float ss0, ss1, ss2, ss3, ss4, ss5, ss6;
        WAVE_SUM7(h0, h1, h2, h3, h4, h5, h6,
                  ss0, ss1, ss2, ss3, ss4, ss5, ss6);

        // SALU window check on wave-uniform bit patterns (inf/0/NaN all fail).
        const unsigned u0 = __float_as_uint(ss0), u1 = __float_as_uint(ss1),
                       u2 = __float_as_uint(ss2), u3 = __float_as_uint(ss3),
                       u4 = __float_as_uint(ss4), u5 = __float_as_uint(ss5),
                       u6 = __float_as_uint(ss6);
        const unsigned umin = min(min(min(u0, u1), min(u2, u3)),
                                  min(min(u4, u5), u6));
        const unsigned umax = max(max(max(u0, u1), max(u2, u3)),
                                  max(max(u4, u5), u6));
        if (umin < SLO || umax > SHI) {
            // Rescue: exact column max, realign, redo sum, refresh scale.
            int C0, C1, C2, C3, C4, C5, C6;
            WAVE_MAXI7(xe0, xe1, xe2, xe3, xe4, xe5, xe6,
                       C0, C1, C2, C3, C4, C5, C6);
            d0 = xe0-C0; d1 = xe1-C1; d2 = xe2-C2; d3 = xe3-C3;
            d4 = xe4-C4; d5 = xe5-C5; d6 = xe6-C6;
            h0 = ldexp_hw(g0, d0); h1 = ldexp_hw(g1, d1);
            h2 = ldexp_hw(g2, d2); h3 = ldexp_hw(g3, d3);
            h4 = ldexp_hw(g4, d4); h5 = ldexp_hw(g5, d5);
            h6 = ldexp_hw(g6, d6);
            WAVE_SUM7(h0, h1, h2, h3, h4, h5, h6,
                      ss0, ss1, ss2, ss3, ss4, ss5, ss6);
            XcS0 = C0; XcS1 = C1; XcS2 = C2; XcS3 = C3;
            XcS4 = C4; XcS5 = C5; XcS6 = C6;
        }

        const float r0 = rcp_hw(ss0), r1 = rcp_hw(ss1), r2 = rcp_hw(ss2),
                    r3 = rcp_hw(ss3), r4 = rcp_hw(ss4), r5 = rcp_hw(ss5),
                    r6 = rcp_hw(ss6);
        const float w0 = (g0*r0)*b2c[0], w1 = (g1*r1)*b2c[1],
                    w2 = (g2*r2)*b2c[2], w3 = (g3*r3)*b2c[3],
                    w4 = (g4*r4)*b2c[4], w5 = (g5*r5)*b2c[5],
                    w6 = (g6*r6)*b2c[6];
        Mm[0] = frexp_mant_hw(w0); iE[0] = frexp_exp_hw(w0) + d0;
        Mm[1] = frexp_mant_hw(w1); iE[1] = frexp_exp_hw(w1) + d1;
        Mm[2] = frexp_mant_hw(w2); iE[2] = frexp_exp_hw(w2) + d2;
        Mm[3] = frexp_mant_hw(w3); iE[3] = frexp_exp_hw(w3) + d3;
        Mm[4] = frexp_mant_hw(w4); iE[4] = frexp_exp_hw(w4) + d4;
        Mm[5] = frexp_mant_hw(w5); iE[5] = frexp_exp_hw(w5) + d5;
        Mm[6] = frexp_mant_hw(w6); iE[6] = frexp_exp_hw(w6) + d6;
    }

    // ---- Switch: U = 2^t = E * 2^-cb = ldexp(M*ib, iE); underflow -> 0. ----
    float U[NB], B[NB];
    #pragma unroll
    for (int j = 0; j < NB; ++j) {
        U[j] = ldexp_hw(Mm[j] * ibc[j], iE[j]);
        B[j] = b2c[j];
    }

    // ---- Phase 2: multiplicative, 80 iterations (unchanged body). ----
    for (int it = 0; it < ITERS2_; ++it) {
        float p0 = U[0] * B[0], p1 = U[1] * B[1], p2 = U[2] * B[2],
              p3 = U[3] * B[3], p4 = U[4] * B[4], p5 = U[5] * B[5],
              p6 = U[6] * B[6];
        const float s = ((p0 + p1) + (p2 + p3)) + ((p4 + p5) + p6);
        const float rs = rcp_hw(s);
        float w0 = U[0] * rs, w1 = U[1] * rs, w2 = U[2] * rs,
              w3 = U[3] * rs, w4 = U[4] * rs, w5 = U[5] * rs,
              w6 = U[6] * rs;

        float ss0, ss1, ss2, ss3, ss4, ss5, ss6;
        WAVE_SUM7_SRC(w0, w1, w2, w3, w4, w5, w6,
                      ss0, ss1, ss2, ss3, ss4, ss5, ss6);

        const float r0 = rcp_hw(ss0);
        const float r1 = rcp_hw(ss1);
        const float r2 = rcp_hw(ss2);
        const float r3 = rcp_hw(ss3);
        const float r4 = rcp_hw(ss4);
        const float r5 = rcp_hw(ss5);
        const float r6 = rcp_hw(ss6);
        U[0] = w0 * r0; U[1] = w1 * r1; U[2] = w2 * r2; U[3] = w3 * r3;
        U[4] = w4 * r4; U[5] = w5 * r5; U[6] = w6 * r6;
    }

    // ---- Epilogue: P = U * bT; normalize by total (+TINY) ----
    float pr[NB];
    float rowsum = 0.f;
    #pragma unroll
    for (int j = 0; j < NB; ++j) {
        pr[j] = U[j] * bT[j];
        rowsum += pr[j];
    }
    const float total = wave_sum_bcast(rowsum);   // ~1 at convergence
    const float inv = 1.0f / (total + TINY_);
    #pragma unroll
    for (int j = 0; j < NB; ++j)
        out[lane * NB + j] = pr[j] * inv;
}

extern "C" void kernel_launch(void* const* d_in, const int* in_sizes, int n_in,
                              void* d_out, int out_size, void* d_ws, size_t ws_size,
                              hipStream_t stream) {
    const float* theta = (const float*)d_in[0];
    const float* phi   = (const float*)d_in[1];
    const float* n     = (const float*)d_in[2];
    const float* sens  = (const float*)d_in[3];
    const float* err   = (const float*)d_in[4];
    float* out = (float*)d_out;

    sinkhorn_kernel<<<1, 64, 0, stream>>>(theta, phi, n, sens, err, out);
}